// Round 13
// baseline (505.304 us; speedup 1.0000x reference)
//
#include <hip/hip_runtime.h>

#define NB 128
#define NT 1024
#define NOBS 512
#define NH 64
#define NP 128
#define NM (NB*NT)      // 131072 rows
#define NN2 256
#define NCH 16
#define CHL 64

typedef short bf16x8 __attribute__((ext_vector_type(8)));
typedef float f32x4 __attribute__((ext_vector_type(4)));

// ---- ws layout (bytes) ----
#define CONST_OFF ((size_t)91226112)
#define CONST_STRIDE ((size_t)131072)
#define WTB_OFF   ((size_t)92274688)
// const block: [0,1024) lambar f32x2; [1024,33792) Bglob bf16 [256][64];
// [33792,66560) Cglob bf16 [64][256]; [66560,74752) gwT bf16 [64][64]

__device__ __forceinline__ unsigned short f2b(float f) {
  unsigned int u = __float_as_uint(f);
  u = u + 0x7fffu + ((u >> 16) & 1u);
  return (unsigned short)(u >> 16);
}
__device__ __forceinline__ float b2f(unsigned short s) {
  return __uint_as_float(((unsigned int)s) << 16);
}
__device__ __forceinline__ unsigned int pk2(float lo, float hi) {
  return (unsigned int)f2b(lo) | ((unsigned int)f2b(hi) << 16);
}

// ---------------- setup: per-layer constant tables + dense W^T bf16 ----------------
__global__ __launch_bounds__(256) void k_setup(const float* Lre, const float* Lim,
    const float* Bp, const float* Cp, const float* lstep, const float* gw,
    const float* dw, unsigned char* wsb) {
  int l = blockIdx.y;
  int idx = blockIdx.x * 256 + threadIdx.x;   // [0,16384)
  unsigned char* cb = wsb + CONST_OFF + (size_t)l * CONST_STRIDE;
  float2* lambar = (float2*)cb;
  unsigned short* Bglob = (unsigned short*)(cb + 1024);
  unsigned short* Cglob = (unsigned short*)(cb + 33792);
  unsigned short* gwT   = (unsigned short*)(cb + 66560);
  {
    int n = idx >> 6, h = idx & 63, p = n >> 1, c = n & 1;
    float step = expf(lstep[l * NP + p]);
    float re = Lre[l * NP + p], im = Lim[l * NP + p];
    float er = expf(re * step), ang = im * step;
    float lbr = er * cosf(ang), lbi = er * sinf(ang);
    if (h == 0 && c == 0) lambar[p] = make_float2(lbr, lbi);
    float den = re * re + im * im;
    float nr = lbr - 1.f, ni = lbi;
    float dr = (nr * re + ni * im) / den;
    float di = (ni * re - nr * im) / den;
    size_t bb = ((size_t)(l * NP + p) * NH + h) * 2;
    float b0 = Bp[bb + 0], b1 = Bp[bb + 1];
    float vr = dr * b0 - di * b1;
    float vi = dr * b1 + di * b0;
    Bglob[n * 64 + h] = f2b(c ? vi : vr);
  }
  {
    int h = idx >> 8, n = idx & 255, p = n >> 1;
    size_t base = ((size_t)(l * NH + h) * NP + p) * 2;
    float val = (n & 1) ? (-2.f * Cp[base + 1]) : (2.f * Cp[base + 0]);
    Cglob[h * 256 + n] = f2b(val);
  }
  if (idx < 4096) {
    int n = idx >> 6, k = idx & 63;
    gwT[n * 64 + k] = f2b(gw[(size_t)(l * NH + k) * NH + n]);
  }
  {
    int idx2 = l * 16384 + idx;
    int h = idx2 >> 9, k = idx2 & 511;
    ((unsigned short*)(wsb + WTB_OFF))[h * 512 + k] = f2b(dw[(size_t)k * NH + h]);
  }
}

// ---------------- dense: x = obs @ W + b (pipelined, BK=64) ----------------
__global__ __launch_bounds__(256) void k_dense(const float* __restrict__ obs,
    const unsigned short* __restrict__ wTb, const float* __restrict__ bias,
    float* __restrict__ xout) {
  __shared__ __align__(16) unsigned short As[128][72];
  __shared__ __align__(16) unsigned short Bs[64][72];
  int tid = threadIdx.x, lane = tid & 63, wv = tid >> 6;
  int row0 = blockIdx.x * 128;
  f32x4 acc[2][4] = {};
  float bcol[4];
#pragma unroll
  for (int ct = 0; ct < 4; ++ct) bcol[ct] = bias[ct * 16 + (lane & 15)];
  float4 ra[8];
  uint4 rb[2];
#pragma unroll
  for (int i = 0; i < 8; ++i) {
    int id = tid + i * 256;
    ra[i] = *(const float4*)(obs + (size_t)(row0 + (id >> 4)) * NOBS + (id & 15) * 4);
  }
#pragma unroll
  for (int i = 0; i < 2; ++i) {
    int id = tid + i * 256;
    rb[i] = *(const uint4*)(wTb + (id >> 3) * 512 + (id & 7) * 8);
  }
  for (int kt = 0; kt < 8; ++kt) {
#pragma unroll
    for (int i = 0; i < 8; ++i) {
      int id = tid + i * 256;
      ushort4 o; o.x = f2b(ra[i].x); o.y = f2b(ra[i].y); o.z = f2b(ra[i].z); o.w = f2b(ra[i].w);
      *(ushort4*)&As[id >> 4][(id & 15) * 4] = o;
    }
#pragma unroll
    for (int i = 0; i < 2; ++i) {
      int id = tid + i * 256;
      *(uint4*)&Bs[id >> 3][(id & 7) * 8] = rb[i];
    }
    __syncthreads();
    if (kt < 7) {
      int k0 = (kt + 1) * 64;
#pragma unroll
      for (int i = 0; i < 8; ++i) {
        int id = tid + i * 256;
        ra[i] = *(const float4*)(obs + (size_t)(row0 + (id >> 4)) * NOBS + k0 + (id & 15) * 4);
      }
#pragma unroll
      for (int i = 0; i < 2; ++i) {
        int id = tid + i * 256;
        rb[i] = *(const uint4*)(wTb + (id >> 3) * 512 + k0 + (id & 7) * 8);
      }
    }
#pragma unroll
    for (int kc = 0; kc < 2; ++kc) {
      bf16x8 a0 = *(const bf16x8*)&As[wv * 32 + (lane & 15)][kc * 32 + (lane >> 4) * 8];
      bf16x8 a1 = *(const bf16x8*)&As[wv * 32 + 16 + (lane & 15)][kc * 32 + (lane >> 4) * 8];
#pragma unroll
      for (int ct = 0; ct < 4; ++ct) {
        bf16x8 bb = *(const bf16x8*)&Bs[ct * 16 + (lane & 15)][kc * 32 + (lane >> 4) * 8];
        acc[0][ct] = __builtin_amdgcn_mfma_f32_16x16x32_bf16(a0, bb, acc[0][ct], 0, 0, 0);
        acc[1][ct] = __builtin_amdgcn_mfma_f32_16x16x32_bf16(a1, bb, acc[1][ct], 0, 0, 0);
      }
    }
    __syncthreads();
  }
  float* Os = (float*)&As[0][0];   // [64][68]
#pragma unroll
  for (int pass = 0; pass < 2; ++pass) {
    if ((wv >> 1) == pass) {
#pragma unroll
      for (int rt = 0; rt < 2; ++rt)
#pragma unroll
        for (int ct = 0; ct < 4; ++ct)
#pragma unroll
          for (int e = 0; e < 4; ++e) {
            int rl = (wv & 1) * 32 + rt * 16 + (lane >> 4) * 4 + e;
            int col = ct * 16 + (lane & 15);
            Os[rl * 68 + col] = acc[rt][ct][e] + bcol[ct];
          }
    }
    __syncthreads();
    {
      int r = tid >> 2, seg = tid & 3;
#pragma unroll
      for (int i = 0; i < 4; ++i)
        *(float4*)(xout + (size_t)(row0 + pass * 64 + r) * NH + seg * 16 + i * 4) =
            *(const float4*)&Os[r * 68 + seg * 16 + i * 4];
    }
    __syncthreads();
  }
}

// ---------------- mega-fused BOTH-layers kernel: R10 skeleton, Cs fragments in regs ----------------
// P1a: w0-3 LN(i)+prefetch           | w4-7 ysMFMA+GELU(i-2)->Ys  (C operand from cfr regs)
// P1b: w4-7 GLU(i-2)+residual+x store
// P2 : w0-3 BuMFMA(i)->BuS[i&1]      | threads 384-511 (waves 6-7) register-scan(i-1)
__global__ __launch_bounds__(512, 1) void k_2layers(float* __restrict__ x,
    const int* __restrict__ dones, const unsigned char* __restrict__ cb0,
    const float* __restrict__ hidden, float* __restrict__ hout,
    const float* __restrict__ nsc0, const float* __restrict__ nbi0,
    const float* __restrict__ Dv0, const float* __restrict__ gb0) {
  __shared__ __align__(16) unsigned short Bs[256][72];      // 36864
  __shared__ __align__(16) unsigned short Cs[64][264];      // 33792 (kept; revert path)
  __shared__ __align__(16) unsigned short BuS[2][64][264];  // 67584
  __shared__ __align__(16) unsigned short xnS[64][72];      // 9216
  __shared__ __align__(16) unsigned short Ys[64][72];       // 9216
  __shared__ float murs[4][64][2];                          // 2048
  __shared__ unsigned int dmask[32];                        // 128  => 158848 B
  int tid = threadIdx.x, lane = tid & 63, wv = tid >> 6;
  int b = blockIdx.x;

  // dones -> bitmask
  {
    unsigned long long m0 = __ballot(dones[b * NT + tid] != 0);
    unsigned long long m1 = __ballot(dones[b * NT + 512 + tid] != 0);
    if (lane == 0) {
      dmask[wv * 2]          = (unsigned int)m0;
      dmask[wv * 2 + 1]      = (unsigned int)(m0 >> 32);
      dmask[16 + wv * 2]     = (unsigned int)m1;
      dmask[16 + wv * 2 + 1] = (unsigned int)(m1 >> 32);
    }
  }

#pragma unroll 1
  for (int l = 0; l < 2; ++l) {
    const unsigned char* cb = cb0 + (size_t)l * CONST_STRIDE;
    const float* nsc = nsc0 + l * NH;
    const float* nbi = nbi0 + l * NH;
    const float* Dv  = Dv0 + l * NH;
    const float* gb  = gb0 + l * NH;
    const unsigned short* Bglob = (const unsigned short*)(cb + 1024);
    const unsigned short* Cglob = (const unsigned short*)(cb + 33792);
    const unsigned short* gwT = (const unsigned short*)(cb + 66560);

    // stage tables for this layer
    {
      int r = tid >> 1, h0 = (tid & 1) * 32;
#pragma unroll
      for (int i = 0; i < 4; ++i)
        *(uint4*)&Bs[r][h0 + i * 8] = *(const uint4*)(Bglob + r * 64 + h0 + i * 8);
    }
    {
      int r = tid >> 3, s0 = (tid & 7) * 32;
#pragma unroll
      for (int i = 0; i < 4; ++i)
        *(uint4*)&Cs[r][s0 + i * 8] = *(const uint4*)(Cglob + r * 256 + s0 + i * 8);
    }

    // role preloads
    float4 pre0, pre1, pre2, pre3;
    float nscr[16], nbir[16];
    float lamr = 0.f, lami = 0.f, hr = 0.f, hi = 0.f;
    float Dr[4], nscc[4], nbic[4], gbr[4];
    bf16x8 gfr[2][4];
    bf16x8 cfr[8][4];   // consumer-resident C fragments (static-indexed after unroll)
    if (tid < 256) {
      int q = tid & 3;
#pragma unroll
      for (int j = 0; j < 16; ++j) { nscr[j] = nsc[q * 16 + j]; nbir[j] = nbi[q * 16 + j]; }
      int r = tid >> 2;
      const float* xr = x + ((size_t)b * NT + r) * NH + q * 16;
      pre0 = *(const float4*)(xr);     pre1 = *(const float4*)(xr + 4);
      pre2 = *(const float4*)(xr + 8); pre3 = *(const float4*)(xr + 12);
    } else {
#pragma unroll
      for (int ct = 0; ct < 4; ++ct) {
        int col = ct * 16 + (lane & 15);
        Dr[ct] = Dv[col]; nscc[ct] = nsc[col]; nbic[ct] = nbi[col]; gbr[ct] = gb[col];
      }
#pragma unroll
      for (int kc = 0; kc < 2; ++kc)
#pragma unroll
        for (int ct = 0; ct < 4; ++ct)
          gfr[kc][ct] = *(const bf16x8*)(gwT + (ct * 16 + (lane & 15)) * 64 + kc * 32 + (lane >> 4) * 8);
#pragma unroll
      for (int kc = 0; kc < 8; ++kc)
#pragma unroll
        for (int ct = 0; ct < 4; ++ct)
          cfr[kc][ct] = *(const bf16x8*)(Cglob + (ct * 16 + (lane & 15)) * 256 + kc * 32 + (lane >> 4) * 8);
      if (tid >= 384) {
        int p = tid - 384;
        float2 lm = ((const float2*)cb)[p];
        lamr = lm.x; lami = lm.y;
        size_t hoff = (((size_t)l * NB + b) * NP + p) * 2;
        hr = hidden[hoff]; hi = hidden[hoff + 1];
      }
    }
    __syncthreads();

#pragma unroll 1
    for (int i = 0; i < NCH + 2; ++i) {
      float yreg[4][4], xres[4][4];
      // ---------------- P1a ----------------
      if (tid < 256) {
        if (i < NCH) {
          float vv[16];
          *(float4*)&vv[0] = pre0;  *(float4*)&vv[4] = pre1;
          *(float4*)&vv[8] = pre2;  *(float4*)&vv[12] = pre3;
          int r = tid >> 2, q = tid & 3;
          if (i < NCH - 1) {
            const float* xr = x + ((size_t)b * NT + (i + 1) * CHL + r) * NH + q * 16;
            pre0 = *(const float4*)(xr);     pre1 = *(const float4*)(xr + 4);
            pre2 = *(const float4*)(xr + 8); pre3 = *(const float4*)(xr + 12);
          }
          float s = 0.f, s2 = 0.f;
#pragma unroll
          for (int j = 0; j < 16; ++j) { s += vv[j]; s2 += vv[j] * vv[j]; }
          s += __shfl_xor(s, 1); s2 += __shfl_xor(s2, 1);
          s += __shfl_xor(s, 2); s2 += __shfl_xor(s2, 2);
          float mu = s * 0.015625f;
          float var = s2 * 0.015625f - mu * mu;
          float rs = rsqrtf(var + 1e-6f);
          if (q == 0) { murs[i & 3][r][0] = mu; murs[i & 3][r][1] = rs; }
#pragma unroll
          for (int k = 0; k < 8; ++k) {
            float a0 = (vv[2 * k] - mu) * rs * nscr[2 * k] + nbir[2 * k];
            float a1 = (vv[2 * k + 1] - mu) * rs * nscr[2 * k + 1] + nbir[2 * k + 1];
            *(unsigned int*)&xnS[r][q * 16 + 2 * k] = pk2(a0, a1);
          }
        }
      } else if (i >= 2) {
        int j = i - 2, wv2 = wv - 4;
#pragma unroll
        for (int ct = 0; ct < 4; ++ct)
#pragma unroll
          for (int e = 0; e < 4; ++e) {
            int rl = wv2 * 16 + (lane >> 4) * 4 + e;
            xres[ct][e] = x[((size_t)b * NT + j * CHL + rl) * NH + ct * 16 + (lane & 15)];
          }
        f32x4 acc[4] = {};
        const unsigned short (*Bu)[264] = BuS[j & 1];
#pragma unroll
        for (int kc = 0; kc < 8; ++kc) {
          bf16x8 a = *(const bf16x8*)&Bu[wv2 * 16 + (lane & 15)][kc * 32 + (lane >> 4) * 8];
#pragma unroll
          for (int ct = 0; ct < 4; ++ct)
            acc[ct] = __builtin_amdgcn_mfma_f32_16x16x32_bf16(a, cfr[kc][ct], acc[ct], 0, 0, 0);
        }
#pragma unroll
        for (int ct = 0; ct < 4; ++ct)
#pragma unroll
          for (int e = 0; e < 4; ++e) {
            int rl = wv2 * 16 + (lane >> 4) * 4 + e;
            float mu = murs[j & 3][rl][0], rs = murs[j & 3][rl][1];
            float xnv = (xres[ct][e] - mu) * rs * nscc[ct] + nbic[ct];
            float yv = acc[ct][e] + Dr[ct] * xnv;
            float t3 = 0.7978845608f * (yv + 0.044715f * yv * yv * yv);
            float u = __expf(2.f * t3);
            yv = 0.5f * yv * (2.f - 2.f / (u + 1.f));
            yreg[ct][e] = yv;
            Ys[rl][ct * 16 + (lane & 15)] = f2b(yv);
          }
      }
      __syncthreads();
      // ---------------- P1b ----------------
      if (tid >= 256 && i >= 2) {
        int j = i - 2, wv2 = wv - 4;
        f32x4 gacc[4] = {};
#pragma unroll
        for (int kc = 0; kc < 2; ++kc) {
          bf16x8 a = *(const bf16x8*)&Ys[wv2 * 16 + (lane & 15)][kc * 32 + (lane >> 4) * 8];
#pragma unroll
          for (int ct = 0; ct < 4; ++ct)
            gacc[ct] = __builtin_amdgcn_mfma_f32_16x16x32_bf16(a, gfr[kc][ct], gacc[ct], 0, 0, 0);
        }
#pragma unroll
        for (int ct = 0; ct < 4; ++ct)
#pragma unroll
          for (int e = 0; e < 4; ++e) {
            int rl = wv2 * 16 + (lane >> 4) * 4 + e;
            float g = gacc[ct][e] + gbr[ct];
            float sg = 1.f / (1.f + __expf(-g));
            x[((size_t)b * NT + j * CHL + rl) * NH + ct * 16 + (lane & 15)] =
                xres[ct][e] + yreg[ct][e] * sg;
          }
      }
      __syncthreads();
      // ---------------- P2 ----------------
      if (tid < 256) {
        if (i < NCH) {
          // BuMFMA(i), swapped operands -> Bu^T tile, packed u32 writes
          f32x4 acc[16] = {};
#pragma unroll
          for (int kc = 0; kc < 2; ++kc) {
            bf16x8 a = *(const bf16x8*)&xnS[wv * 16 + (lane & 15)][kc * 32 + (lane >> 4) * 8];
#pragma unroll
            for (int ct = 0; ct < 16; ++ct) {
              bf16x8 bbf = *(const bf16x8*)&Bs[ct * 16 + (lane & 15)][kc * 32 + (lane >> 4) * 8];
              acc[ct] = __builtin_amdgcn_mfma_f32_16x16x32_bf16(bbf, a, acc[ct], 0, 0, 0);
            }
          }
          unsigned short (*Bu)[264] = BuS[i & 1];
          int t = wv * 16 + (lane & 15), cb4 = (lane >> 4) * 4;
#pragma unroll
          for (int ct = 0; ct < 16; ++ct) {
            *(unsigned int*)&Bu[t][ct * 16 + cb4]     = pk2(acc[ct][0], acc[ct][1]);
            *(unsigned int*)&Bu[t][ct * 16 + cb4 + 2] = pk2(acc[ct][2], acc[ct][3]);
          }
        }
      } else if (tid >= 384 && i >= 1 && i <= NCH) {
        // register-bulk scan(ch=i-1) on BuS[(i-1)&1], waves 6-7 (consumer-class, R10-proven slot)
        int ch = i - 1, p = tid - 384;
        unsigned short (*Bu)[264] = BuS[ch & 1];
        unsigned int m0 = dmask[ch * 2], m1 = dmask[ch * 2 + 1];
#pragma unroll 1
        for (int half = 0; half < 2; ++half) {
          unsigned int msk = half ? m1 : m0;
          int t0 = half * 32;
          unsigned int v[32];
#pragma unroll
          for (int t = 0; t < 32; ++t) v[t] = *(const unsigned int*)&Bu[t0 + t][2 * p];
#pragma unroll
          for (int t = 0; t < 32; ++t) {
            float bur = b2f((unsigned short)(v[t] & 0xffffu));
            float bui = b2f((unsigned short)(v[t] >> 16));
            bool d = ((msk >> t) & 1u) != 0;
            float nr = lamr * hr - lami * hi + bur;
            float ni = lamr * hi + lami * hr + bui;
            hr = d ? bur : nr;
            hi = d ? bui : ni;
            v[t] = pk2(hr, hi);
          }
#pragma unroll
          for (int t = 0; t < 32; ++t) *(unsigned int*)&Bu[t0 + t][2 * p] = v[t];
        }
        if (ch == NCH - 1) {
          size_t hoff = (((size_t)l * NB + b) * NP + p) * 2;
          hout[hoff] = hr; hout[hoff + 1] = hi;
        }
      }
      __syncthreads();
    }
  }
}

extern "C" void kernel_launch(void* const* d_in, const int* in_sizes, int n_in,
                              void* d_out, int out_size, void* d_ws, size_t ws_size,
                              hipStream_t stream) {
  const float* obs    = (const float*)d_in[0];
  const int*   dones  = (const int*)d_in[1];
  const float* hidden = (const float*)d_in[2];
  const float* dw     = (const float*)d_in[3];
  const float* db     = (const float*)d_in[4];
  const float* Lre    = (const float*)d_in[5];
  const float* Lim    = (const float*)d_in[6];
  const float* Bp     = (const float*)d_in[7];
  const float* Cp     = (const float*)d_in[8];
  const float* Dv     = (const float*)d_in[9];
  const float* lstep  = (const float*)d_in[10];
  const float* nsc    = (const float*)d_in[11];
  const float* nbi    = (const float*)d_in[12];
  const float* gw     = (const float*)d_in[13];
  const float* gb     = (const float*)d_in[14];

  float* hout = (float*)d_out;
  float* x = hout + (size_t)2 * NB * NP * 2;   // 65536 floats offset

  unsigned char* wsb = (unsigned char*)d_ws;
  unsigned short* wTb = (unsigned short*)(wsb + WTB_OFF);

  k_setup<<<dim3(64, 2), 256, 0, stream>>>(Lre, Lim, Bp, Cp, lstep, gw, dw, wsb);
  k_dense<<<NM / 128, 256, 0, stream>>>(obs, wTb, db, x);
  k_2layers<<<NB, 512, 0, stream>>>(x, dones, wsb + CONST_OFF, hidden, hout,
                                    nsc, nbi, Dv, gb);
}

// Round 14
// 268.215 us; speedup vs baseline: 1.8839x; 1.8839x over previous
//
#include <hip/hip_runtime.h>

#define NB 128
#define NT 1024
#define NOBS 512
#define NH 64
#define NP 128
#define NM (NB*NT)      // 131072 rows
#define NN2 256
#define NCH 16
#define CHL 64

typedef short bf16x8 __attribute__((ext_vector_type(8)));
typedef float f32x4 __attribute__((ext_vector_type(4)));

// ---- ws layout (bytes) ----
#define BU_OFF    ((size_t)0)              // 131072*256 bf16 = 67108864
#define AGGA_OFF  ((size_t)83886080)       // 128*16*128 float2 = 2097152
#define AGGB_OFF  ((size_t)85983232)       // 2097152
#define AGGC_OFF  ((size_t)88080384)       // 1048576
#define HIN_OFF   ((size_t)89128960)       // 2097152
#define CONST_OFF ((size_t)91226112)
#define CONST_STRIDE ((size_t)131072)
#define WTB_OFF   ((size_t)92274688)       // 65536
#define GM_OFF    ((size_t)92340224)       // 128*16*2 u32 = 16384 (dones bitmask)
// const block: [0,1024) lambar f32x2; [1024,33792) Bglob bf16 [256][64];
// [33792,66560) Cglob bf16 [64][256]; [66560,74752) gwT bf16 [64][64]

__device__ __forceinline__ unsigned short f2b(float f) {
  unsigned int u = __float_as_uint(f);
  u = u + 0x7fffu + ((u >> 16) & 1u);
  return (unsigned short)(u >> 16);
}
__device__ __forceinline__ float b2f(unsigned short s) {
  return __uint_as_float(((unsigned int)s) << 16);
}
__device__ __forceinline__ unsigned int pk2(float lo, float hi) {
  return (unsigned int)f2b(lo) | ((unsigned int)f2b(hi) << 16);
}

// ---------------- setup: const tables + dense W^T + dones bitmask ----------------
__global__ __launch_bounds__(256) void k_setup(const float* Lre, const float* Lim,
    const float* Bp, const float* Cp, const float* lstep, const float* gw,
    const float* dw, const int* dones, unsigned char* wsb) {
  int l = blockIdx.y;
  int idx = blockIdx.x * 256 + threadIdx.x;   // [0,16384)
  unsigned char* cb = wsb + CONST_OFF + (size_t)l * CONST_STRIDE;
  float2* lambar = (float2*)cb;
  unsigned short* Bglob = (unsigned short*)(cb + 1024);
  unsigned short* Cglob = (unsigned short*)(cb + 33792);
  unsigned short* gwT   = (unsigned short*)(cb + 66560);
  {
    int n = idx >> 6, h = idx & 63, p = n >> 1, c = n & 1;
    float step = expf(lstep[l * NP + p]);
    float re = Lre[l * NP + p], im = Lim[l * NP + p];
    float er = expf(re * step), ang = im * step;
    float lbr = er * cosf(ang), lbi = er * sinf(ang);
    if (h == 0 && c == 0) lambar[p] = make_float2(lbr, lbi);
    float den = re * re + im * im;
    float nr = lbr - 1.f, ni = lbi;
    float dr = (nr * re + ni * im) / den;
    float di = (ni * re - nr * im) / den;
    size_t bb = ((size_t)(l * NP + p) * NH + h) * 2;
    float b0 = Bp[bb + 0], b1 = Bp[bb + 1];
    float vr = dr * b0 - di * b1;
    float vi = dr * b1 + di * b0;
    Bglob[n * 64 + h] = f2b(c ? vi : vr);
  }
  {
    int h = idx >> 8, n = idx & 255, p = n >> 1;
    size_t base = ((size_t)(l * NH + h) * NP + p) * 2;
    float val = (n & 1) ? (-2.f * Cp[base + 1]) : (2.f * Cp[base + 0]);
    Cglob[h * 256 + n] = f2b(val);
  }
  if (idx < 4096) {
    int n = idx >> 6, k = idx & 63;
    gwT[n * 64 + k] = f2b(gw[(size_t)(l * NH + k) * NH + n]);
  }
  {
    int idx2 = l * 16384 + idx;
    int h = idx2 >> 9, k = idx2 & 511;
    ((unsigned short*)(wsb + WTB_OFF))[h * 512 + k] = f2b(dw[(size_t)k * NH + h]);
  }
  if (l == 0 && idx < 4096) {
    // gmask[b*32 + ch*2 + half] bit j = dones[b,ch*64+half*32+j]
    int b = idx >> 5, w = idx & 31;
    const int* dp = dones + b * NT + w * 32;
    unsigned int m = 0;
#pragma unroll
    for (int j = 0; j < 32; ++j) m |= (dp[j] != 0 ? 1u : 0u) << j;
    ((unsigned int*)(wsb + GM_OFF))[idx] = m;
  }
}

// ---------------- dense: x = obs @ W + b (pipelined, BK=64; R3-proven) ----------------
__global__ __launch_bounds__(256) void k_dense(const float* __restrict__ obs,
    const unsigned short* __restrict__ wTb, const float* __restrict__ bias,
    float* __restrict__ xout) {
  __shared__ __align__(16) unsigned short As[128][72];
  __shared__ __align__(16) unsigned short Bs[64][72];
  int tid = threadIdx.x, lane = tid & 63, wv = tid >> 6;
  int row0 = blockIdx.x * 128;
  f32x4 acc[2][4] = {};
  float bcol[4];
#pragma unroll
  for (int ct = 0; ct < 4; ++ct) bcol[ct] = bias[ct * 16 + (lane & 15)];
  float4 ra[8];
  uint4 rb[2];
#pragma unroll
  for (int i = 0; i < 8; ++i) {
    int id = tid + i * 256;
    ra[i] = *(const float4*)(obs + (size_t)(row0 + (id >> 4)) * NOBS + (id & 15) * 4);
  }
#pragma unroll
  for (int i = 0; i < 2; ++i) {
    int id = tid + i * 256;
    rb[i] = *(const uint4*)(wTb + (id >> 3) * 512 + (id & 7) * 8);
  }
  for (int kt = 0; kt < 8; ++kt) {
#pragma unroll
    for (int i = 0; i < 8; ++i) {
      int id = tid + i * 256;
      ushort4 o; o.x = f2b(ra[i].x); o.y = f2b(ra[i].y); o.z = f2b(ra[i].z); o.w = f2b(ra[i].w);
      *(ushort4*)&As[id >> 4][(id & 15) * 4] = o;
    }
#pragma unroll
    for (int i = 0; i < 2; ++i) {
      int id = tid + i * 256;
      *(uint4*)&Bs[id >> 3][(id & 7) * 8] = rb[i];
    }
    __syncthreads();
    if (kt < 7) {
      int k0 = (kt + 1) * 64;
#pragma unroll
      for (int i = 0; i < 8; ++i) {
        int id = tid + i * 256;
        ra[i] = *(const float4*)(obs + (size_t)(row0 + (id >> 4)) * NOBS + k0 + (id & 15) * 4);
      }
#pragma unroll
      for (int i = 0; i < 2; ++i) {
        int id = tid + i * 256;
        rb[i] = *(const uint4*)(wTb + (id >> 3) * 512 + k0 + (id & 7) * 8);
      }
    }
#pragma unroll
    for (int kc = 0; kc < 2; ++kc) {
      bf16x8 a0 = *(const bf16x8*)&As[wv * 32 + (lane & 15)][kc * 32 + (lane >> 4) * 8];
      bf16x8 a1 = *(const bf16x8*)&As[wv * 32 + 16 + (lane & 15)][kc * 32 + (lane >> 4) * 8];
#pragma unroll
      for (int ct = 0; ct < 4; ++ct) {
        bf16x8 bb = *(const bf16x8*)&Bs[ct * 16 + (lane & 15)][kc * 32 + (lane >> 4) * 8];
        acc[0][ct] = __builtin_amdgcn_mfma_f32_16x16x32_bf16(a0, bb, acc[0][ct], 0, 0, 0);
        acc[1][ct] = __builtin_amdgcn_mfma_f32_16x16x32_bf16(a1, bb, acc[1][ct], 0, 0, 0);
      }
    }
    __syncthreads();
  }
  float* Os = (float*)&As[0][0];   // [64][68]
#pragma unroll
  for (int pass = 0; pass < 2; ++pass) {
    if ((wv >> 1) == pass) {
#pragma unroll
      for (int rt = 0; rt < 2; ++rt)
#pragma unroll
        for (int ct = 0; ct < 4; ++ct)
#pragma unroll
          for (int e = 0; e < 4; ++e) {
            int rl = (wv & 1) * 32 + rt * 16 + (lane >> 4) * 4 + e;
            int col = ct * 16 + (lane & 15);
            Os[rl * 68 + col] = acc[rt][ct][e] + bcol[ct];
          }
    }
    __syncthreads();
    {
      int r = tid >> 2, seg = tid & 3;
#pragma unroll
      for (int i = 0; i < 4; ++i)
        *(float4*)(xout + (size_t)(row0 + pass * 64 + r) * NH + seg * 16 + i * 4) =
            *(const float4*)&Os[r * 68 + seg * 16 + i * 4];
    }
    __syncthreads();
  }
}

// ---------------- lnbu_scan1: LN + BuMFMA (reg B-frags) + chunk aggregate ----------------
// 2048 blocks (b,ch), 256 threads, LDS ~48KB -> 3 blocks/CU
__global__ __launch_bounds__(256, 3) void k_lnbu_scan1(const float* __restrict__ x,
    const float* __restrict__ nsc, const float* __restrict__ nbi,
    const unsigned char* __restrict__ cb, const unsigned int* __restrict__ gmask,
    unsigned short* __restrict__ bu,
    float2* __restrict__ aggA, float2* __restrict__ aggB, float* __restrict__ aggC) {
  __shared__ __align__(16) unsigned short xnS[64][72];   // 9216
  __shared__ __align__(16) unsigned short BuS[64][264];  // 33792
  __shared__ float pA[256][2], pB[256][2], pC[256];      // 5120
  int tid = threadIdx.x, lane = tid & 63, wv = tid >> 6;
  int row0 = blockIdx.x * 64;
  int b = blockIdx.x >> 4, ch = blockIdx.x & 15;
  const unsigned short* Bglob = (const unsigned short*)(cb + 1024);
  // B fragments in regs: wave owns p-tiles wv*4..wv*4+3 (32 VGPR)
  bf16x8 bfr[4][2];
#pragma unroll
  for (int ptl = 0; ptl < 4; ++ptl)
#pragma unroll
    for (int kc = 0; kc < 2; ++kc)
      bfr[ptl][kc] = *(const bf16x8*)(Bglob + ((wv * 4 + ptl) * 16 + (lane & 15)) * 64
                                      + kc * 32 + (lane >> 4) * 8);
  // LN: 4 threads/row (R3-proven), pk2 writes
  {
    int r = tid >> 2, q = tid & 3;
    const float* xr = x + (size_t)(row0 + r) * NH + q * 16;
    float4 vv[4];
#pragma unroll
    for (int i = 0; i < 4; ++i) vv[i] = *(const float4*)(xr + i * 4);
    const float* vp = (const float*)vv;
    float s = 0.f, s2 = 0.f;
#pragma unroll
    for (int j = 0; j < 16; ++j) { s += vp[j]; s2 += vp[j] * vp[j]; }
    s += __shfl_xor(s, 1); s2 += __shfl_xor(s2, 1);
    s += __shfl_xor(s, 2); s2 += __shfl_xor(s2, 2);
    float mu = s * 0.015625f;
    float var = s2 * 0.015625f - mu * mu;
    float rs = rsqrtf(var + 1e-6f);
#pragma unroll
    for (int k = 0; k < 8; ++k) {
      float a0 = (vp[2 * k] - mu) * rs * nsc[q * 16 + 2 * k] + nbi[q * 16 + 2 * k];
      float a1 = (vp[2 * k + 1] - mu) * rs * nsc[q * 16 + 2 * k + 1] + nbi[q * 16 + 2 * k + 1];
      *(unsigned int*)&xnS[r][q * 16 + 2 * k] = pk2(a0, a1);
    }
  }
  __syncthreads();
  // BuMFMA swapped: out (p-tile, t-tile); acc[ptl][tt]
  f32x4 acc[4][4] = {};
#pragma unroll
  for (int kc = 0; kc < 2; ++kc)
#pragma unroll
    for (int tt = 0; tt < 4; ++tt) {
      bf16x8 a = *(const bf16x8*)&xnS[tt * 16 + (lane & 15)][kc * 32 + (lane >> 4) * 8];
#pragma unroll
      for (int ptl = 0; ptl < 4; ++ptl)
        acc[ptl][tt] = __builtin_amdgcn_mfma_f32_16x16x32_bf16(bfr[ptl][kc], a, acc[ptl][tt], 0, 0, 0);
    }
  // write Bu^T tile: row t, col p (packed u32; R7/R10-proven layout)
  {
    int cb4 = (lane >> 4) * 4;
#pragma unroll
    for (int ptl = 0; ptl < 4; ++ptl)
#pragma unroll
      for (int tt = 0; tt < 4; ++tt) {
        int t = tt * 16 + (lane & 15);
        int pc = (wv * 4 + ptl) * 16 + cb4;
        *(unsigned int*)&BuS[t][pc]     = pk2(acc[ptl][tt][0], acc[ptl][tt][1]);
        *(unsigned int*)&BuS[t][pc + 2] = pk2(acc[ptl][tt][2], acc[ptl][tt][3]);
      }
  }
  __syncthreads();
  // bounce BuS -> HBM (coalesced; R3-proven)
  {
    int r = tid >> 2, seg = tid & 3;
#pragma unroll
    for (int i = 0; i < 8; ++i)
      *(uint4*)(bu + (size_t)(row0 + r) * NN2 + seg * 64 + i * 8) =
          *(const uint4*)&BuS[r][seg * 64 + i * 8];
  }
  // chunk aggregate: 2 halves x 32 steps, register-bulk, bitmask resets
  {
    int p = tid & 127, half = tid >> 7, t0 = half * 32;
    float2 lam = ((const float2*)cb)[p];
    unsigned int msk = gmask[(b * NCH + ch) * 2 + half];
    unsigned int v[32];
#pragma unroll
    for (int t = 0; t < 32; ++t) v[t] = *(const unsigned int*)&BuS[t0 + t][2 * p];
    float Ar = 1.f, Ai = 0.f, br = 0.f, bi = 0.f, c = 0.f;
#pragma unroll
    for (int t = 0; t < 32; ++t) {
      float bur = b2f((unsigned short)(v[t] & 0xffffu));
      float bui = b2f((unsigned short)(v[t] >> 16));
      bool d = ((msk >> t) & 1u) != 0;
      float nAr = lam.x * Ar - lam.y * Ai;
      float nAi = lam.x * Ai + lam.y * Ar;
      float nbr = lam.x * br - lam.y * bi + bur;
      float nbi2 = lam.x * bi + lam.y * br + bui;
      Ar = d ? lam.x : nAr; Ai = d ? lam.y : nAi;
      br = d ? bur : nbr;  bi = d ? bui : nbi2;
      c  = d ? 1.f : c;
    }
    pA[tid][0] = Ar; pA[tid][1] = Ai; pB[tid][0] = br; pB[tid][1] = bi; pC[tid] = c;
  }
  __syncthreads();
  if (tid < 128) {
    float A0r = pA[tid][0], A0i = pA[tid][1], b0r = pB[tid][0], b0i = pB[tid][1], c0 = pC[tid];
    float A1r = pA[tid + 128][0], A1i = pA[tid + 128][1];
    float b1r = pB[tid + 128][0], b1i = pB[tid + 128][1], c1 = pC[tid + 128];
    float Ar, Ai, br, bi, c;
    if (c1 != 0.f) { Ar = A1r; Ai = A1i; br = b1r; bi = b1i; c = 1.f; }
    else {
      Ar = A1r * A0r - A1i * A0i; Ai = A1r * A0i + A1i * A0r;
      br = A1r * b0r - A1i * b0i + b1r; bi = A1r * b0i + A1i * b0r + b1i;
      c = c0;
    }
    int o = (b * NCH + ch) * NP + tid;
    aggA[o] = make_float2(Ar, Ai);
    aggB[o] = make_float2(br, bi);
    aggC[o] = c;
  }
}

// ---------------- scan chunks: cross-chunk prefix + h_out (R1-proven) ----------------
__global__ __launch_bounds__(256) void k_scanchunks(const float* __restrict__ hidden,
    const float2* __restrict__ aggA, const float2* __restrict__ aggB,
    const float* __restrict__ aggC, float2* __restrict__ hin,
    float* __restrict__ hout, int l) {
  int gid = blockIdx.x * 256 + threadIdx.x;   // [0,16384)
  int b = gid >> 7, p = gid & 127;
  size_t hoff = ((size_t)(l * NB + b) * NP + p) * 2;
  float hr = hidden[hoff], hi = hidden[hoff + 1];
  for (int ch = 0; ch < NCH; ++ch) {
    int o = (b * NCH + ch) * NP + p;
    hin[o] = make_float2(hr, hi);
    float2 A = aggA[o]; float2 bb = aggB[o]; float c = aggC[o];
    if (c != 0.f) { hr = bb.x; hi = bb.y; }
    else {
      float nr = A.x * hr - A.y * hi + bb.x;
      hi = A.x * hi + A.y * hr + bb.y; hr = nr;
    }
  }
  hout[hoff] = hr; hout[hoff + 1] = hi;
}

// ---------------- ysglu_scan2: scan2 (reg-bulk) + ys (reg C-frags) + GELU + GLU + residual ----------------
// 2048 blocks (b,ch), 256 threads, LDS ~44KB -> 3 blocks/CU
__global__ __launch_bounds__(256, 3) void k_ysglu_scan2(const unsigned short* __restrict__ bu,
    const unsigned int* __restrict__ gmask, const unsigned char* __restrict__ cb,
    const float2* __restrict__ hin,
    const float* __restrict__ nsc, const float* __restrict__ nbi,
    const float* __restrict__ Dv, const float* __restrict__ gb,
    float* __restrict__ x) {
  __shared__ __align__(16) unsigned short BuS[64][264];  // 33792
  __shared__ __align__(16) unsigned short Ys[64][72];    // 9216
  __shared__ float muS[64], rsS[64];                     // 512
  int tid = threadIdx.x, lane = tid & 63, wv = tid >> 6;
  int row0 = blockIdx.x * 64;
  int b = blockIdx.x >> 4, ch = blockIdx.x & 15;
  const unsigned short* Cglob = (const unsigned short*)(cb + 33792);
  const unsigned short* gwT = (const unsigned short*)(cb + 66560);
  // C/G fragments in regs: wave owns col strip ct=wv (32+8 VGPR)
  bf16x8 cfr[8], gfr[2];
#pragma unroll
  for (int kc = 0; kc < 8; ++kc)
    cfr[kc] = *(const bf16x8*)(Cglob + (wv * 16 + (lane & 15)) * 256 + kc * 32 + (lane >> 4) * 8);
#pragma unroll
  for (int kc = 0; kc < 2; ++kc)
    gfr[kc] = *(const bf16x8*)(gwT + (wv * 16 + (lane & 15)) * 64 + kc * 32 + (lane >> 4) * 8);
  float Dc, nscc, nbic, gbc;
  {
    int col = wv * 16 + (lane & 15);
    Dc = Dv[col]; nscc = nsc[col]; nbic = nbi[col]; gbc = gb[col];
  }
  // load bu tile -> LDS
  {
    int r = tid >> 2, seg = tid & 3;
#pragma unroll
    for (int i = 0; i < 8; ++i)
      *(uint4*)&BuS[r][seg * 64 + i * 8] =
          *(const uint4*)(bu + (size_t)(row0 + r) * NN2 + seg * 64 + i * 8);
  }
  // x strip preload (residual + LN re-apply)
  float xres[4][4];
#pragma unroll
  for (int rt = 0; rt < 4; ++rt)
#pragma unroll
    for (int e = 0; e < 4; ++e) {
      int rl = rt * 16 + (lane >> 4) * 4 + e;
      xres[rt][e] = x[(size_t)(row0 + rl) * NH + wv * 16 + (lane & 15)];
    }
  // LN stats: 4 threads/row (R2/R3-proven)
  {
    int r = tid >> 2, q = tid & 3;
    const float* xr = x + (size_t)(row0 + r) * NH + q * 16;
    float4 vv[4];
#pragma unroll
    for (int i = 0; i < 4; ++i) vv[i] = *(const float4*)(xr + i * 4);
    const float* vp = (const float*)vv;
    float s = 0.f, s2 = 0.f;
#pragma unroll
    for (int j = 0; j < 16; ++j) { s += vp[j]; s2 += vp[j] * vp[j]; }
    s += __shfl_xor(s, 1); s2 += __shfl_xor(s2, 1);
    s += __shfl_xor(s, 2); s2 += __shfl_xor(s2, 2);
    float mu = s * 0.015625f;
    float var = s2 * 0.015625f - mu * mu;
    if (q == 0) { muS[r] = mu; rsS[r] = rsqrtf(var + 1e-6f); }
  }
  float2 hseed;
  if (tid < 128) hseed = hin[(b * NCH + ch) * NP + tid];
  __syncthreads();
  // scan2 register-bulk: threads 0-127, column 2p, two 32-step halves
  if (tid < 128) {
    int p = tid;
    float2 lam = ((const float2*)cb)[p];
    unsigned int m0 = gmask[(b * NCH + ch) * 2], m1 = gmask[(b * NCH + ch) * 2 + 1];
    float hr = hseed.x, hi = hseed.y;
#pragma unroll 1
    for (int half = 0; half < 2; ++half) {
      unsigned int msk = half ? m1 : m0;
      int t0 = half * 32;
      unsigned int v[32];
#pragma unroll
      for (int t = 0; t < 32; ++t) v[t] = *(const unsigned int*)&BuS[t0 + t][2 * p];
#pragma unroll
      for (int t = 0; t < 32; ++t) {
        float bur = b2f((unsigned short)(v[t] & 0xffffu));
        float bui = b2f((unsigned short)(v[t] >> 16));
        bool d = ((msk >> t) & 1u) != 0;
        float nr = lam.x * hr - lam.y * hi + bur;
        float ni = lam.x * hi + lam.y * hr + bui;
        hr = d ? bur : nr;
        hi = d ? bui : ni;
        v[t] = pk2(hr, hi);
      }
#pragma unroll
      for (int t = 0; t < 32; ++t) *(unsigned int*)&BuS[t0 + t][2 * p] = v[t];
    }
  }
  __syncthreads();
  // ys: wave = col strip wv, 4 row-tiles; C operand from regs
  f32x4 acc[4] = {};
#pragma unroll
  for (int kc = 0; kc < 8; ++kc)
#pragma unroll
    for (int rt = 0; rt < 4; ++rt) {
      bf16x8 a = *(const bf16x8*)&BuS[rt * 16 + (lane & 15)][kc * 32 + (lane >> 4) * 8];
      acc[rt] = __builtin_amdgcn_mfma_f32_16x16x32_bf16(a, cfr[kc], acc[rt], 0, 0, 0);
    }
  float yreg[4][4];
#pragma unroll
  for (int rt = 0; rt < 4; ++rt)
#pragma unroll
    for (int e = 0; e < 4; ++e) {
      int rl = rt * 16 + (lane >> 4) * 4 + e;
      float xnv = (xres[rt][e] - muS[rl]) * rsS[rl] * nscc + nbic;
      float yv = acc[rt][e] + Dc * xnv;
      float t3 = 0.7978845608f * (yv + 0.044715f * yv * yv * yv);
      float u = __expf(2.f * t3);
      yv = 0.5f * yv * (2.f - 2.f / (u + 1.f));
      yreg[rt][e] = yv;
      Ys[rl][wv * 16 + (lane & 15)] = f2b(yv);
    }
  __syncthreads();
  // GLU (reads Ys across barrier) + residual -> Os (aliases BuS, reads done)
  float* Os = (float*)&BuS[0][0];   // [64][66] stride
  f32x4 gacc[4] = {};
#pragma unroll
  for (int kc = 0; kc < 2; ++kc)
#pragma unroll
    for (int rt = 0; rt < 4; ++rt) {
      bf16x8 a = *(const bf16x8*)&Ys[rt * 16 + (lane & 15)][kc * 32 + (lane >> 4) * 8];
      gacc[rt] = __builtin_amdgcn_mfma_f32_16x16x32_bf16(a, gfr[kc], gacc[rt], 0, 0, 0);
    }
#pragma unroll
  for (int rt = 0; rt < 4; ++rt)
#pragma unroll
    for (int e = 0; e < 4; ++e) {
      int rl = rt * 16 + (lane >> 4) * 4 + e;
      float g = gacc[rt][e] + gbc;
      float sg = 1.f / (1.f + __expf(-g));
      Os[rl * 66 + wv * 16 + (lane & 15)] = xres[rt][e] + yreg[rt][e] * sg;
    }
  __syncthreads();
  {
    int r = tid >> 2, seg = tid & 3;
#pragma unroll
    for (int i = 0; i < 4; ++i)
      *(float4*)(x + (size_t)(row0 + r) * NH + seg * 16 + i * 4) =
          *(const float4*)&Os[r * 66 + seg * 16 + i * 4];
  }
}

extern "C" void kernel_launch(void* const* d_in, const int* in_sizes, int n_in,
                              void* d_out, int out_size, void* d_ws, size_t ws_size,
                              hipStream_t stream) {
  const float* obs    = (const float*)d_in[0];
  const int*   dones  = (const int*)d_in[1];
  const float* hidden = (const float*)d_in[2];
  const float* dw     = (const float*)d_in[3];
  const float* db     = (const float*)d_in[4];
  const float* Lre    = (const float*)d_in[5];
  const float* Lim    = (const float*)d_in[6];
  const float* Bp     = (const float*)d_in[7];
  const float* Cp     = (const float*)d_in[8];
  const float* Dv     = (const float*)d_in[9];
  const float* lstep  = (const float*)d_in[10];
  const float* nsc    = (const float*)d_in[11];
  const float* nbi    = (const float*)d_in[12];
  const float* gw     = (const float*)d_in[13];
  const float* gb     = (const float*)d_in[14];

  float* hout = (float*)d_out;
  float* x = hout + (size_t)2 * NB * NP * 2;   // 65536 floats offset

  unsigned char* wsb = (unsigned char*)d_ws;
  unsigned short* bu = (unsigned short*)(wsb + BU_OFF);
  float2* aggA = (float2*)(wsb + AGGA_OFF);
  float2* aggB = (float2*)(wsb + AGGB_OFF);
  float*  aggC = (float*)(wsb + AGGC_OFF);
  float2* hin  = (float2*)(wsb + HIN_OFF);
  unsigned short* wTb = (unsigned short*)(wsb + WTB_OFF);
  const unsigned int* gmask = (const unsigned int*)(wsb + GM_OFF);

  k_setup<<<dim3(64, 2), 256, 0, stream>>>(Lre, Lim, Bp, Cp, lstep, gw, dw, dones, wsb);
  k_dense<<<NM / 128, 256, 0, stream>>>(obs, wTb, db, x);
  for (int l = 0; l < 2; ++l) {
    const unsigned char* cb = wsb + CONST_OFF + (size_t)l * CONST_STRIDE;
    k_lnbu_scan1<<<NM / 64, 256, 0, stream>>>(x, nsc + l * NH, nbi + l * NH, cb, gmask,
                                              bu, aggA, aggB, aggC);
    k_scanchunks<<<NB * NP / 256, 256, 0, stream>>>(hidden, aggA, aggB, aggC, hin, hout, l);
    k_ysglu_scan2<<<NM / 64, 256, 0, stream>>>(bu, gmask, cb, hin,
                                               nsc + l * NH, nbi + l * NH,
                                               Dv + l * NH, gb + l * NH, x);
  }
}